// Round 19
// baseline (1087.877 us; speedup 1.0000x reference)
//
#include <hip/hip_runtime.h>
#include <hip/hip_bf16.h>
#include <math.h>

// babyGPT-50m forward: B=2 T=1024 V=50257 C=768 H=12 L=6 D=64
#define Bsz 2
#define Tt 1024
#define Vv 50257
#define Cc 768
#define Hh 12
#define Ll 6
#define NTOK (Bsz*Tt)
#define VPAD 50304   // multiple of 128 for the head tile

typedef __attribute__((ext_vector_type(8))) short bf16x8;
typedef __attribute__((ext_vector_type(8))) unsigned short u16x8;
typedef __attribute__((ext_vector_type(4))) unsigned short u16x4;
typedef __attribute__((ext_vector_type(4))) float f32x4;
typedef unsigned short u16;

static __device__ __forceinline__ u16 f2bf(float f){
  unsigned u = __float_as_uint(f);
  u += 0x7FFF + ((u >> 16) & 1);   // RNE
  return (u16)(u >> 16);
}
static __device__ __forceinline__ float bf2f(u16 h){
  return __uint_as_float(((unsigned)h) << 16);
}

// async global->LDS, 16B per lane; LDS dest is wave-uniform base + lane*16
#define GL16(g,l) __builtin_amdgcn_global_load_lds( \
    (const __attribute__((address_space(1))) void*)(g), \
    (__attribute__((address_space(3))) void*)(l), 16, 0, 0)
#define WAITVM(n) asm volatile("s_waitcnt vmcnt(%0)" :: "n"(n) : "memory")

// ---------------- embedding: x = tok_emb[idx] + pos_emb (fp32) ----------------
__global__ void embed_kernel(const int* __restrict__ idx, const float* __restrict__ tok,
                             const float* __restrict__ pos, float* __restrict__ x){
  const int C4 = Cc/4;
  int i = blockIdx.x * 256 + threadIdx.x;
  if (i >= NTOK*C4) return;
  int tk = i / C4, c4 = i % C4;
  int row = idx[tk];
  int t = tk % Tt;
  float4 a = ((const float4*)tok)[(size_t)row*C4 + c4];
  float4 p = ((const float4*)pos)[(size_t)t*C4 + c4];
  float4 r; r.x=a.x+p.x; r.y=a.y+p.y; r.z=a.z+p.z; r.w=a.w+p.w;
  ((float4*)x)[i] = r;
}

// ---------------- layernorm: fp32 in -> bf16 out ----------------
__global__ void ln_kernel(const float* __restrict__ in, const float* __restrict__ g,
                          const float* __restrict__ bt, u16* __restrict__ out){
  int row = blockIdx.x, tid = threadIdx.x;
  const float* r = in + (size_t)row*Cc;
  float v0=r[tid], v1=r[tid+256], v2=r[tid+512];
  float s  = v0+v1+v2;
  float s2 = v0*v0+v1*v1+v2*v2;
  #pragma unroll
  for (int off=32; off; off>>=1){ s += __shfl_xor(s,off); s2 += __shfl_xor(s2,off); }
  __shared__ float red[8];
  int wid = tid >> 6;
  if ((tid & 63) == 0){ red[wid]=s; red[4+wid]=s2; }
  __syncthreads();
  float S  = red[0]+red[1]+red[2]+red[3];
  float S2 = red[4]+red[5]+red[6]+red[7];
  float mean = S * (1.0f/Cc);
  float var  = S2 * (1.0f/Cc) - mean*mean;
  float rstd = rsqrtf(var + 1e-5f);
  u16* o = out + (size_t)row*Cc;
  o[tid]     = f2bf((v0-mean)*rstd*g[tid]     + bt[tid]);
  o[tid+256] = f2bf((v1-mean)*rstd*g[tid+256] + bt[tid+256]);
  o[tid+512] = f2bf((v2-mean)*rstd*g[tid+512] + bt[tid+512]);
}

// ---- weight transpose+convert tile body: fp32 [K][N] -> bf16 [Npad][K]; 64x64 ----
// one-shot stream: nontemporal loads/stores to avoid L2 pollution
__device__ __forceinline__ void wtrans_tile(const float* __restrict__ inp, u16* __restrict__ op,
                                            int K, int N, int Npad, int n0, int k0,
                                            u16 (*t)[68], int tid){
  #pragma unroll
  for (int i=0;i<4;i++){
    int e = tid + 256*i;
    int k = e >> 4, n4 = (e & 15) * 4;
    int n = n0 + n4;
    const float* rowp = inp + (size_t)(k0+k)*N;
    f32x4 v;
    if (n + 3 < N) v = __builtin_nontemporal_load((const f32x4*)&rowp[n]);
    else {
      v[0] = (n   < N) ? rowp[n  ] : 0.f;
      v[1] = (n+1 < N) ? rowp[n+1] : 0.f;
      v[2] = (n+2 < N) ? rowp[n+2] : 0.f;
      v[3] = (n+3 < N) ? rowp[n+3] : 0.f;
    }
    u16x4 pk; pk[0]=f2bf(v[0]); pk[1]=f2bf(v[1]); pk[2]=f2bf(v[2]); pk[3]=f2bf(v[3]);
    *(u16x4*)&t[k][n4] = pk;
  }
  __syncthreads();
  #pragma unroll
  for (int i=0;i<2;i++){
    int e = tid + 256*i;
    int n = e >> 3, k8 = (e & 7) * 8;
    u16x8 pk;
    #pragma unroll
    for (int q=0;q<8;q++) pk[q] = t[k8+q][n];
    if (n0 + n < Npad)
      __builtin_nontemporal_store(pk, (u16x8*)&op[(size_t)(n0+n)*K + k0 + k8]);
  }
}

__global__ void wtrans_kernel(const float* __restrict__ in, u16* __restrict__ out,
                              int K, int N, int Npad, size_t lsi, size_t lso){
  __shared__ u16 t[64][68];
  wtrans_tile(in + (size_t)blockIdx.z*lsi, out + (size_t)blockIdx.z*lso,
              K, N, Npad, blockIdx.x*64, blockIdx.y*64, t, threadIdx.x);
}

// batched 768x768 transposes: z = which*6 + layer over {Wq,Wk,Wv,Wp}
__global__ void wtrans4_kernel(const float* __restrict__ Wq, const float* __restrict__ Wk,
                               const float* __restrict__ Wv, const float* __restrict__ Wp,
                               u16* __restrict__ wqkvT, u16* __restrict__ wpT){
  __shared__ u16 t[64][68];
  int z = blockIdx.z;
  int which = z / Ll, l = z - which*Ll;
  const float* in = (which==0 ? Wq : which==1 ? Wk : which==2 ? Wv : Wp) + (size_t)l*Cc*Cc;
  u16* out = (which < 3) ? wqkvT + (size_t)l*2304*768 + (size_t)which*768*768
                         : wpT + (size_t)l*768*768;
  wtrans_tile(in, out, 768, 768, 768, blockIdx.x*64, blockIdx.y*64, t, threadIdx.x);
}

// ---------------- bias concat [L][2304] ----------------
__global__ void bconcat_kernel(const float* __restrict__ bq, const float* __restrict__ bk,
                               const float* __restrict__ bv, float* __restrict__ o){
  int i = blockIdx.x*256 + threadIdx.x;
  if (i >= Ll*2304) return;
  int l = i/2304, j = i - l*2304;
  o[i] = (j < 768) ? bq[l*768+j] : (j < 1536) ? bk[l*768+j-768] : bv[l*768+j-1536];
}

// ---------------- flash attention, QB=64 ----------------
// XCD-chunk swizzle (bh-locality) + heavy-first; setprio(1) around MFMA clusters (T5).
__global__ __launch_bounds__(256) void flash_kernel(
    const u16* __restrict__ qkv, const u16* __restrict__ vT, u16* __restrict__ y){
  __shared__ u16 Ks[2][64*64];
  __shared__ u16 Vs[2][64*64];
  __shared__ u16 Ps[4][16*64];
  int gx = gridDim.x;
  int flat = blockIdx.y*gx + blockIdx.x;
  int nwg = gx*gridDim.y;
  int qq = nwg >> 3, rr = nwg & 7;
  int xcd = flat & 7, lid = flat >> 3;
  int swz = (xcd < rr) ? xcd*(qq+1) + lid : rr*(qq+1) + (xcd-rr)*qq + lid;
  int bx = (gx - 1) - (swz % gx);          // heavy-first
  int bh = swz / gx;
  int b = bh/Hh, h = bh - b*Hh;
  int q0 = bx*64;
  int tid = threadIdx.x, lane = tid&63, wid = tid>>6;
  const size_t tokbase = (size_t)b*Tt;
  int arow = lane&15, akof = (lane>>4)*8;
  bf16x8 qa[2];
  #pragma unroll
  for (int ks=0;ks<2;ks++)
    qa[ks] = *(const bf16x8*)&qkv[(tokbase + q0 + wid*16 + arow)*2304
                                  + h*64 + ks*32 + akof];
  int srow = lane>>3;
  int sbyte = ((lane&7)*16) ^ (srow<<4);
  const u16* kbase = qkv + tokbase*2304 + 768 + h*64;
  const u16* vbase = vT + (size_t)bh*64*Tt;
  auto STAGEKV = [&](int t, int bb){
    int j0 = t*64;
    #pragma unroll
    for (int c=0;c<2;c++){
      int r = wid*16 + c*8 + srow;
      GL16(kbase + (size_t)(j0 + r)*2304 + (sbyte>>1), &Ks[bb][(wid*16 + c*8)*64]);
      GL16(vbase + (size_t)r*Tt + j0 + (sbyte>>1),     &Vs[bb][(wid*16 + c*8)*64]);
    }
  };
  float m_r[4], l_r[4];
  f32x4 o_acc[4] = {};
  #pragma unroll
  for (int jj=0;jj<4;jj++){ m_r[jj] = -1e30f; l_r[jj] = 0.f; }

  int njt = bx + 1;
  STAGEKV(0, 0);
  asm volatile("s_waitcnt vmcnt(0)" ::: "memory");
  __builtin_amdgcn_s_barrier();
  for (int t=0; t<njt; t++){
    int cur = t&1;
    if (t+1 < njt) STAGEKV(t+1, cur^1);
    int j0 = t*64;
    f32x4 sacc[4] = {};
    #pragma unroll
    for (int ks=0;ks<2;ks++){
      bf16x8 kf[4];
      #pragma unroll
      for (int ni=0;ni<4;ni++){
        int s16 = ni*16 + (lane&15);
        int kb = (ks*64 + (lane>>4)*16) ^ ((s16&7)<<4);
        kf[ni] = *(const bf16x8*)((const char*)&Ks[cur][0] + s16*128 + kb);
      }
      __builtin_amdgcn_s_setprio(1);
      #pragma unroll
      for (int ni=0;ni<4;ni++)
        sacc[ni] = __builtin_amdgcn_mfma_f32_16x16x32_bf16(qa[ks], kf[ni], sacc[ni], 0,0,0);
      __builtin_amdgcn_s_setprio(0);
    }
    float tmax[4];
    #pragma unroll
    for (int jj=0;jj<4;jj++) tmax[jj] = -1e30f;
    #pragma unroll
    for (int ni=0;ni<4;ni++)
      #pragma unroll
      for (int jj=0;jj<4;jj++){
        float v = sacc[ni][jj]*0.125f;
        int sg = j0 + ni*16 + (lane&15);
        int tg = q0 + wid*16 + (lane>>4)*4 + jj;
        v = (sg <= tg) ? v : -1e30f;
        sacc[ni][jj] = v;
        tmax[jj] = fmaxf(tmax[jj], v);
      }
    #pragma unroll
    for (int jj=0;jj<4;jj++){
      float tm = tmax[jj];
      tm = fmaxf(tm, __shfl_xor(tm,1)); tm = fmaxf(tm, __shfl_xor(tm,2));
      tm = fmaxf(tm, __shfl_xor(tm,4)); tm = fmaxf(tm, __shfl_xor(tm,8));
      float mn = fmaxf(m_r[jj], tm);
      float al = __expf(m_r[jj] - mn);
      m_r[jj] = mn;
      l_r[jj] *= al;
      tmax[jj] = al;
    }
    float tsum[4] = {};
    #pragma unroll
    for (int ni=0;ni<4;ni++)
      #pragma unroll
      for (int jj=0;jj<4;jj++){
        float p = __expf(sacc[ni][jj] - m_r[jj]);
        tsum[jj] += p;
        int pr = (lane>>4)*4 + jj;
        int pcb = (2*(ni*16 + (lane&15))) ^ ((pr&7)<<4);
        *(u16*)((char*)&Ps[wid][0] + pr*128 + pcb) = f2bf(p);
      }
    #pragma unroll
    for (int jj=0;jj<4;jj++){
      float ts = tsum[jj];
      ts += __shfl_xor(ts,1); ts += __shfl_xor(ts,2);
      ts += __shfl_xor(ts,4); ts += __shfl_xor(ts,8);
      l_r[jj] += ts;
      float al = tmax[jj];
      #pragma unroll
      for (int ni2=0;ni2<4;ni2++) o_acc[ni2][jj] *= al;
    }
    #pragma unroll
    for (int ks2=0;ks2<2;ks2++){
      bf16x8 pa, vf[4];
      int prr = lane&15;
      int pb = (ks2*64 + (lane>>4)*16) ^ ((prr&7)<<4);
      pa = *(const bf16x8*)((const char*)&Ps[wid][0] + prr*128 + pb);
      #pragma unroll
      for (int ni2=0;ni2<4;ni2++){
        int d16 = ni2*16 + (lane&15);
        int sb = (ks2*64 + (lane>>4)*16) ^ ((d16&7)<<4);
        vf[ni2] = *(const bf16x8*)((const char*)&Vs[cur][0] + d16*128 + sb);
      }
      __builtin_amdgcn_s_setprio(1);
      #pragma unroll
      for (int ni2=0;ni2<4;ni2++)
        o_acc[ni2] = __builtin_amdgcn_mfma_f32_16x16x32_bf16(pa, vf[ni2], o_acc[ni2], 0,0,0);
      __builtin_amdgcn_s_setprio(0);
    }
    asm volatile("s_waitcnt vmcnt(0) lgkmcnt(0)" ::: "memory");
    __builtin_amdgcn_s_barrier();
  }
  #pragma unroll
  for (int jj=0;jj<4;jj++){
    float inv = 1.0f / l_r[jj];
    int tok2 = q0 + wid*16 + (lane>>4)*4 + jj;
    size_t rb = (tokbase + tok2)*Cc + h*64;
    #pragma unroll
    for (int ni2=0;ni2<4;ni2++)
      y[rb + ni2*16 + (lane&15)] = f2bf(o_acc[ni2][jj] * inv);
  }
}

// -------- MFMA GEMM: BMxBN tile, BK in {32,64}, swizzled LDS rows, NBUF pipeline --------
template<int NBUF, int NTHR, int WN, int BM, int BN, int BK,
         bool BIAS, bool RESID, bool GELU, bool OUTBF, bool ROWSCAN, bool VFUSE>
__global__ __launch_bounds__(NTHR) void mm_kernel(
    const u16* __restrict__ A, const u16* __restrict__ Bm,
    const float* __restrict__ bias, const float* __restrict__ resid,
    void* __restrict__ out, u16* __restrict__ vt,
    int N, int K, int lda, int ldb, int ldc)
{
  constexpr int WAVES = NTHR/64;
  constexpr int WM    = WAVES/WN;
  constexpr int FM    = BM/(WM*16);
  constexpr int FN    = BN/(WN*16);
  constexpr int KSTEPS = BK/32;
  constexpr int CPW   = FN*16;
  constexpr int ESTR  = CPW + 4;
  constexpr int ABUF  = BM*BK;
  constexpr int BBUF  = BN*BK;
  constexpr int ARPW  = BM/WAVES;
  constexpr int BRPW  = BN/WAVES;
  constexpr int RPC   = (BK==64) ? 8 : 16;
  constexpr int ACALLS = ARPW/RPC;
  constexpr int BCALLS = BRPW/RPC;
  constexpr int LOADS = ACALLS + BCALLS;
  constexpr int SMEM_STAGE = NBUF*(ABUF+BBUF)*2;
  constexpr int SMEM_EPI   = WAVES*16*ESTR*4;
  constexpr int SMEMB = SMEM_STAGE > SMEM_EPI ? SMEM_STAGE : SMEM_EPI;
  __shared__ __align__(16) char smem[SMEMB];
  u16* As = (u16*)smem;
  u16* Bs = As + NBUF*ABUF;

  int bx = blockIdx.x, by = blockIdx.y;
  {                                    // bijective XCD swizzle (m204)
    int gx = gridDim.x;
    int nwg = gx * gridDim.y;
    int flat = by*gx + bx;
    int qq = nwg >> 3, rr = nwg & 7;
    int xcd = flat & 7, lid = flat >> 3;
    int swz = (xcd < rr) ? xcd*(qq+1) + lid : rr*(qq+1) + (xcd-rr)*qq + lid;
    bx = swz % gx; by = swz / gx;
  }
  int m0 = bx*BM, n0 = by*BN;
  int tid = threadIdx.x, lane = tid & 63, wid = tid >> 6;
  int r0 = (wid/WN)*(BM/WM), c0 = (wid%WN)*(BN/WN);
  int lrow = lane & 15;
  int rl, sswz;
  if constexpr (BK==64){ rl = lane>>3; sswz = ((lane&7) ^ (lane>>3)) * 8; }
  else                 { rl = lane>>2; sswz = ((lane&3) ^ ((lane>>3)&3)) * 8; }
  const u16* Ap = A + (size_t)(m0 + wid*ARPW + rl)*lda + sswz;
  const u16* Bp = Bm + (size_t)(n0 + wid*BRPW + rl)*ldb + sswz;
  int nt = K/BK;
  auto STAGE = [&](int t, int bb){
    int kk = t*BK;
    u16* Al = As + bb*ABUF + (wid*ARPW)*BK;
    #pragma unroll
    for (int c=0;c<ACALLS;c++)
      GL16(Ap + kk + (size_t)(c*RPC)*lda, Al + c*512);
    u16* Bl = Bs + bb*BBUF + (wid*BRPW)*BK;
    #pragma unroll
    for (int c=0;c<BCALLS;c++)
      GL16(Bp + kk + (size_t)(c*RPC)*ldb, Bl + c*512);
  };
  f32x4 acc[FM][FN] = {};
  if constexpr (NBUF==2){
    STAGE(0, 0);
    WAITVM(0);
    __builtin_amdgcn_s_barrier();
  } else {
    STAGE(0, 0);
    if (nt > 1) STAGE(1, 1);
    WAITVM(LOADS);
    __builtin_amdgcn_s_barrier();
  }
  for (int t = 0; t < nt; t++){
    int bb = (NBUF==2) ? (t & 1) : (t % 3);
    if constexpr (NBUF==2){
      if (t+1 < nt) STAGE(t+1, (t+1)&1);
    } else {
      if (t+2 < nt) STAGE(t+2, (t+2)%3);
    }
    const char* Ab2 = (const char*)(As + bb*ABUF);
    const char* Bb2 = (const char*)(Bs + bb*BBUF);
    #pragma unroll
    for (int ks=0;ks<KSTEPS;ks++){
      int cof;
      if constexpr (BK==64) cof = ((ks*4 + (lane>>4)) ^ (lane&7)) << 4;
      else                  cof = ((lane>>4) ^ (((lane&15)>>1)&3)) << 4;
      bf16x8 af[FM], bfr[FN];
      #pragma unroll
      for (int m=0;m<FM;m++) af[m] = *(const bf16x8*)(Ab2 + (r0 + m*16 + lrow)*(BK*2) + cof);
      #pragma unroll
      for (int n=0;n<FN;n++) bfr[n] = *(const bf16x8*)(Bb2 + (c0 + n*16 + lrow)*(BK*2) + cof);
      #pragma unroll
      for (int m=0;m<FM;m++)
        #pragma unroll
        for (int n=0;n<FN;n++)
          acc[m][n] = __builtin_amdgcn_mfma_f32_16x16x32_bf16(af[m], bfr[n], acc[m][n], 0,0,0);
    }
    if constexpr (NBUF==2){
      asm volatile("s_waitcnt vmcnt(0) lgkmcnt(0)" ::: "memory");
    } else {
      if (t+2 < nt) WAITVM(LOADS); else WAITVM(0);
    }
    __builtin_amdgcn_s_barrier();
  }

  // ---- epilogue: per-wave-private LDS transpose tile, coalesced stores ----
  float* ebuf = (float*)smem + wid*16*ESTR;
  int er = lane >> 2;
  int ec = (lane & 3) * (CPW/4);
  #pragma unroll
  for (int m=0;m<FM;m++){
    #pragma unroll
    for (int n=0;n<FN;n++)
      #pragma unroll
      for (int j=0;j<4;j++)
        ebuf[((lane>>4)*4+j)*ESTR + n*16 + (lane&15)] = acc[m][n][j];
    __builtin_amdgcn_s_waitcnt(0);     // lgkm drain for own-wave LDS RAW
    if constexpr (ROWSCAN){
      #pragma unroll
      for (int rr2=0; rr2<16; rr2++){
        int gr2 = m0 + r0 + m*16 + rr2;
        int gc2 = n0 + c0 + lane;
        float v = ebuf[rr2*ESTR + lane];
        if (gc2 < N)
          __builtin_nontemporal_store(v, &((float*)out)[(size_t)gr2*ldc + gc2]);
      }
    } else {
      int grow = m0 + r0 + m*16 + er;
      int gcol = n0 + c0 + ec;
      size_t rbase = (size_t)grow*ldc;
      if constexpr (OUTBF){
        u16 tmp[CPW/4];
        #pragma unroll
        for (int q=0;q<FN;q++){
          float4 v = *(const float4*)&ebuf[er*ESTR + ec + q*4];
          float f0=v.x, f1=v.y, f2=v.z, f3=v.w;
          if (BIAS){
            float4 b4 = *(const float4*)&bias[gcol + q*4];
            f0+=b4.x; f1+=b4.y; f2+=b4.z; f3+=b4.w;
          }
          if (GELU){
            f0 = 0.5f*f0*(1.f+erff(f0*0.70710678118654752f));
            f1 = 0.5f*f1*(1.f+erff(f1*0.70710678118654752f));
            f2 = 0.5f*f2*(1.f+erff(f2*0.70710678118654752f));
            f3 = 0.5f*f3*(1.f+erff(f3*0.70710678118654752f));
          }
          tmp[q*4+0]=f2bf(f0); tmp[q*4+1]=f2bf(f1);
          tmp[q*4+2]=f2bf(f2); tmp[q*4+3]=f2bf(f3);
        }
        // v-region (cols>=1536) is only consumed via vT -> skip qkv store there
        if (!VFUSE || gcol < 1536){
          #pragma unroll
          for (int s2=0; s2<CPW/32; s2++)
            *(u16x8*)&((u16*)out)[rbase + gcol + s2*8] = *(const u16x8*)&tmp[s2*8];
        }
        if constexpr (VFUSE){
          if (gcol >= 1536){
            int hh = (gcol - 1536) >> 6;
            int d0 = (gcol - 1536) & 63;
            int b  = grow >> 10;          // Tt = 1024
            int tt = grow & (Tt-1);
            u16* vp = vt + ((size_t)(b*Hh + hh)*64 + d0)*Tt + tt;
            #pragma unroll
            for (int i=0;i<CPW/4;i++)
              vp[(size_t)i*Tt] = tmp[i];
          }
        }
      } else {
        #pragma unroll
        for (int q=0;q<FN;q++){
          float4 v = *(const float4*)&ebuf[er*ESTR + ec + q*4];
          float f0=v.x, f1=v.y, f2=v.z, f3=v.w;
          if (BIAS){
            float4 b4 = *(const float4*)&bias[gcol + q*4];
            f0+=b4.x; f1+=b4.y; f2+=b4.z; f3+=b4.w;
          }
          if (GELU){
            f0 = 0.5f*f0*(1.f+erff(f0*0.70710678118654752f));
            f1 = 0.5f*f1*(1.f+erff(f1*0.70710678118654752f));
            f2 = 0.5f*f2*(1.f+erff(f2*0.70710678118654752f));
            f3 = 0.5f*f3*(1.f+erff(f3*0.70710678118654752f));
          }
          if (RESID){
            float4 r4 = *(const float4*)&resid[rbase + gcol + q*4];
            f0+=r4.x; f1+=r4.y; f2+=r4.z; f3+=r4.w;
          }
          float4 o4; o4.x=f0; o4.y=f1; o4.z=f2; o4.w=f3;
          *(float4*)&((float*)out)[rbase + gcol + q*4] = o4;
        }
      }
    }
  }
}

// ---------------- orchestration ----------------
extern "C" void kernel_launch(void* const* d_in, const int* in_sizes, int n_in,
                              void* d_out, int out_size, void* d_ws, size_t ws_size,
                              hipStream_t stream){
  const int*   idx  = (const int*)d_in[0];
  const float* tok  = (const float*)d_in[1];
  const float* pos  = (const float*)d_in[2];
  const float* ln1g = (const float*)d_in[3];
  const float* ln1b = (const float*)d_in[4];
  const float* Wq   = (const float*)d_in[5];
  const float* bq   = (const float*)d_in[6];
  const float* Wk   = (const float*)d_in[7];
  const float* bk   = (const float*)d_in[8];
  const float* Wv   = (const float*)d_in[9];
  const float* bv   = (const float*)d_in[10];
  const float* Wp   = (const float*)d_in[11];
  const float* bp   = (const float*)d_in[12];
  const float* ln2g = (const float*)d_in[13];
  const float* ln2b = (const float*)d_in[14];
  const float* Wf1  = (const float*)d_in[15];
  const float* bf1  = (const float*)d_in[16];
  const float* Wf2  = (const float*)d_in[17];
  const float* bf2  = (const float*)d_in[18];
  const float* lnfg = (const float*)d_in[19];
  const float* lnfb = (const float*)d_in[20];
  const float* headW= (const float*)d_in[21];
  float* outp = (float*)d_out;

  char* w = (char*)d_ws;
  u16* wqkvT = (u16*)w;  w += (size_t)Ll*2304*768*2;
  u16* wpT   = (u16*)w;  w += (size_t)Ll*768*768*2;
  u16* wf1T  = (u16*)w;  w += (size_t)Ll*3072*768*2;
  u16* wf2T  = (u16*)w;  w += (size_t)Ll*768*3072*2;
  u16* headT = (u16*)w;  w += (size_t)VPAD*768*2;
  float* bqkv= (float*)w;w += (size_t)Ll*2304*4;
  float* x   = (float*)w;w += (size_t)NTOK*Cc*4;
  u16* h     = (u16*)w;  w += (size_t)NTOK*Cc*2;
  u16* qkv   = (u16*)w;  w += (size_t)NTOK*2304*2;
  u16* vT    = (u16*)w;  w += (size_t)Bsz*Hh*64*Tt*2;
  u16* y     = (u16*)w;  w += (size_t)NTOK*Cc*2;
  u16* ff    = (u16*)w;  w += (size_t)NTOK*4*Cc*2;

  wtrans4_kernel<<<dim3(12,12,4*Ll), 256, 0, stream>>>(Wq, Wk, Wv, Wp, wqkvT, wpT);
  wtrans_kernel<<<dim3(48,12,Ll), 256, 0, stream>>>(Wf1, wf1T,          768, 3072, 3072, (size_t)Cc*4*Cc, (size_t)3072*768);
  wtrans_kernel<<<dim3(12,48,Ll), 256, 0, stream>>>(Wf2, wf2T,          3072, 768, 768, (size_t)4*Cc*Cc, (size_t)768*3072);
  wtrans_kernel<<<dim3(VPAD/64,12,1), 256, 0, stream>>>(headW, headT, 768, Vv, VPAD, 0, 0);
  bconcat_kernel<<<(Ll*2304+255)/256, 256, 0, stream>>>(bq, bk, bv, bqkv);

  embed_kernel<<<NTOK*(Cc/4)/256, 256, 0, stream>>>(idx, tok, pos, x);

  for (int l=0;l<Ll;l++){
    ln_kernel<<<NTOK, 256, 0, stream>>>(x, ln1g+l*Cc, ln1b+l*Cc, h);
    // qkv GEMM with fused v-transpose into vT (v-region global store skipped)
    mm_kernel<2,256,2,64,128,64,true,false,false,true,false,true><<<dim3(32,18,1), 256, 0, stream>>>(
        h, wqkvT+(size_t)l*2304*768, bqkv+l*2304, nullptr, qkv, vT, 2304, 768, 768, 768, 2304);
    flash_kernel<<<dim3(Tt/64, Bsz*Hh), 256, 0, stream>>>(qkv, vT, y);
    mm_kernel<3,256,2,64,64,64,true,true,false,false,false,false><<<dim3(32,12,1), 256, 0, stream>>>(
        y, wpT+(size_t)l*768*768, bp+l*Cc, x, x, nullptr, 768, 768, 768, 768, 768);
    ln_kernel<<<NTOK, 256, 0, stream>>>(x, ln2g+l*Cc, ln2b+l*Cc, h);
    mm_kernel<2,256,2,64,128,64,true,false,true,true,false,false><<<dim3(32,24,1), 256, 0, stream>>>(
        h, wf1T+(size_t)l*3072*768, bf1+(size_t)l*4*Cc, nullptr, ff, nullptr, 3072, 768, 768, 768, 3072);
    mm_kernel<3,256,2,64,64,64,true,true,false,false,false,false><<<dim3(32,12,1), 256, 0, stream>>>(
        ff, wf2T+(size_t)l*768*3072, bf2+l*Cc, x, x, nullptr, 768, 3072, 3072, 3072, 768);
  }
  ln_kernel<<<NTOK, 256, 0, stream>>>(x, lnfg, lnfb, h);
  // head: R9 optimum — 128x128 tile, BK=32 swz, NBUF=2, 32KB LDS, 4 waves, 5 blk/CU
  mm_kernel<2,256,2,128,128,32,false,false,false,false,true,false><<<dim3(16,VPAD/128,1), 256, 0, stream>>>(
      h, headT, nullptr, nullptr, outp, nullptr, Vv, 768, 768, 768, Vv);
}

// Round 20
// 1079.489 us; speedup vs baseline: 1.0078x; 1.0078x over previous
//
#include <hip/hip_runtime.h>
#include <hip/hip_bf16.h>
#include <math.h>

// babyGPT-50m forward: B=2 T=1024 V=50257 C=768 H=12 L=6 D=64
#define Bsz 2
#define Tt 1024
#define Vv 50257
#define Cc 768
#define Hh 12
#define Ll 6
#define NTOK (Bsz*Tt)
#define VPAD 50304   // multiple of 128 for the head tile

typedef __attribute__((ext_vector_type(8))) short bf16x8;
typedef __attribute__((ext_vector_type(8))) unsigned short u16x8;
typedef __attribute__((ext_vector_type(4))) unsigned short u16x4;
typedef __attribute__((ext_vector_type(4))) float f32x4;
typedef unsigned short u16;

static __device__ __forceinline__ u16 f2bf(float f){
  unsigned u = __float_as_uint(f);
  u += 0x7FFF + ((u >> 16) & 1);   // RNE
  return (u16)(u >> 16);
}
static __device__ __forceinline__ float bf2f(u16 h){
  return __uint_as_float(((unsigned)h) << 16);
}

// async global->LDS, 16B per lane; LDS dest is wave-uniform base + lane*16
#define GL16(g,l) __builtin_amdgcn_global_load_lds( \
    (const __attribute__((address_space(1))) void*)(g), \
    (__attribute__((address_space(3))) void*)(l), 16, 0, 0)
#define WAITVM(n) asm volatile("s_waitcnt vmcnt(%0)" :: "n"(n) : "memory")

// ---------------- embedding: x = tok_emb[idx] + pos_emb (fp32) ----------------
__global__ void embed_kernel(const int* __restrict__ idx, const float* __restrict__ tok,
                             const float* __restrict__ pos, float* __restrict__ x){
  const int C4 = Cc/4;
  int i = blockIdx.x * 256 + threadIdx.x;
  if (i >= NTOK*C4) return;
  int tk = i / C4, c4 = i % C4;
  int row = idx[tk];
  int t = tk % Tt;
  float4 a = ((const float4*)tok)[(size_t)row*C4 + c4];
  float4 p = ((const float4*)pos)[(size_t)t*C4 + c4];
  float4 r; r.x=a.x+p.x; r.y=a.y+p.y; r.z=a.z+p.z; r.w=a.w+p.w;
  ((float4*)x)[i] = r;
}

// ---------------- layernorm: fp32 in -> bf16 out ----------------
__global__ void ln_kernel(const float* __restrict__ in, const float* __restrict__ g,
                          const float* __restrict__ bt, u16* __restrict__ out){
  int row = blockIdx.x, tid = threadIdx.x;
  const float* r = in + (size_t)row*Cc;
  float v0=r[tid], v1=r[tid+256], v2=r[tid+512];
  float s  = v0+v1+v2;
  float s2 = v0*v0+v1*v1+v2*v2;
  #pragma unroll
  for (int off=32; off; off>>=1){ s += __shfl_xor(s,off); s2 += __shfl_xor(s2,off); }
  __shared__ float red[8];
  int wid = tid >> 6;
  if ((tid & 63) == 0){ red[wid]=s; red[4+wid]=s2; }
  __syncthreads();
  float S  = red[0]+red[1]+red[2]+red[3];
  float S2 = red[4]+red[5]+red[6]+red[7];
  float mean = S * (1.0f/Cc);
  float var  = S2 * (1.0f/Cc) - mean*mean;
  float rstd = rsqrtf(var + 1e-5f);
  u16* o = out + (size_t)row*Cc;
  o[tid]     = f2bf((v0-mean)*rstd*g[tid]     + bt[tid]);
  o[tid+256] = f2bf((v1-mean)*rstd*g[tid+256] + bt[tid+256]);
  o[tid+512] = f2bf((v2-mean)*rstd*g[tid+512] + bt[tid+512]);
}

// ---- weight transpose+convert tile body: fp32 [K][N] -> bf16 [Npad][K]; 64x64 ----
__device__ __forceinline__ void wtrans_tile(const float* __restrict__ inp, u16* __restrict__ op,
                                            int K, int N, int Npad, int n0, int k0,
                                            u16 (*t)[68], int tid){
  #pragma unroll
  for (int i=0;i<4;i++){
    int e = tid + 256*i;
    int k = e >> 4, n4 = (e & 15) * 4;
    int n = n0 + n4;
    const float* rowp = inp + (size_t)(k0+k)*N;
    float4 v;
    if (n + 3 < N) v = *(const float4*)&rowp[n];
    else {
      v.x = (n   < N) ? rowp[n  ] : 0.f;
      v.y = (n+1 < N) ? rowp[n+1] : 0.f;
      v.z = (n+2 < N) ? rowp[n+2] : 0.f;
      v.w = (n+3 < N) ? rowp[n+3] : 0.f;
    }
    u16x4 pk; pk[0]=f2bf(v.x); pk[1]=f2bf(v.y); pk[2]=f2bf(v.z); pk[3]=f2bf(v.w);
    *(u16x4*)&t[k][n4] = pk;
  }
  __syncthreads();
  #pragma unroll
  for (int i=0;i<2;i++){
    int e = tid + 256*i;
    int n = e >> 3, k8 = (e & 7) * 8;
    u16x8 pk;
    #pragma unroll
    for (int q=0;q<8;q++) pk[q] = t[k8+q][n];
    if (n0 + n < Npad)
      *(u16x8*)&op[(size_t)(n0+n)*K + k0 + k8] = pk;
  }
}

__global__ void wtrans_kernel(const float* __restrict__ in, u16* __restrict__ out,
                              int K, int N, int Npad, size_t lsi, size_t lso){
  __shared__ u16 t[64][68];
  wtrans_tile(in + (size_t)blockIdx.z*lsi, out + (size_t)blockIdx.z*lso,
              K, N, Npad, blockIdx.x*64, blockIdx.y*64, t, threadIdx.x);
}

// batched 768x768 transposes: z = which*6 + layer over {Wq,Wk,Wv,Wp}
__global__ void wtrans4_kernel(const float* __restrict__ Wq, const float* __restrict__ Wk,
                               const float* __restrict__ Wv, const float* __restrict__ Wp,
                               u16* __restrict__ wqkvT, u16* __restrict__ wpT){
  __shared__ u16 t[64][68];
  int z = blockIdx.z;
  int which = z / Ll, l = z - which*Ll;
  const float* in = (which==0 ? Wq : which==1 ? Wk : which==2 ? Wv : Wp) + (size_t)l*Cc*Cc;
  u16* out = (which < 3) ? wqkvT + (size_t)l*2304*768 + (size_t)which*768*768
                         : wpT + (size_t)l*768*768;
  wtrans_tile(in, out, 768, 768, 768, blockIdx.x*64, blockIdx.y*64, t, threadIdx.x);
}

// ---------------- bias concat [L][2304] ----------------
__global__ void bconcat_kernel(const float* __restrict__ bq, const float* __restrict__ bk,
                               const float* __restrict__ bv, float* __restrict__ o){
  int i = blockIdx.x*256 + threadIdx.x;
  if (i >= Ll*2304) return;
  int l = i/2304, j = i - l*2304;
  o[i] = (j < 768) ? bq[l*768+j] : (j < 1536) ? bk[l*768+j-768] : bv[l*768+j-1536];
}

// ---------------- flash attention, QB=64 ----------------
// XCD-chunk swizzle (bh-locality) + heavy-first; setprio(1) around MFMA clusters (T5).
__global__ __launch_bounds__(256) void flash_kernel(
    const u16* __restrict__ qkv, const u16* __restrict__ vT, u16* __restrict__ y){
  __shared__ u16 Ks[2][64*64];
  __shared__ u16 Vs[2][64*64];
  __shared__ u16 Ps[4][16*64];
  int gx = gridDim.x;
  int flat = blockIdx.y*gx + blockIdx.x;
  int nwg = gx*gridDim.y;
  int qq = nwg >> 3, rr = nwg & 7;
  int xcd = flat & 7, lid = flat >> 3;
  int swz = (xcd < rr) ? xcd*(qq+1) + lid : rr*(qq+1) + (xcd-rr)*qq + lid;
  int bx = (gx - 1) - (swz % gx);          // heavy-first
  int bh = swz / gx;
  int b = bh/Hh, h = bh - b*Hh;
  int q0 = bx*64;
  int tid = threadIdx.x, lane = tid&63, wid = tid>>6;
  const size_t tokbase = (size_t)b*Tt;
  int arow = lane&15, akof = (lane>>4)*8;
  bf16x8 qa[2];
  #pragma unroll
  for (int ks=0;ks<2;ks++)
    qa[ks] = *(const bf16x8*)&qkv[(tokbase + q0 + wid*16 + arow)*2304
                                  + h*64 + ks*32 + akof];
  int srow = lane>>3;
  int sbyte = ((lane&7)*16) ^ (srow<<4);
  const u16* kbase = qkv + tokbase*2304 + 768 + h*64;
  const u16* vbase = vT + (size_t)bh*64*Tt;
  auto STAGEKV = [&](int t, int bb){
    int j0 = t*64;
    #pragma unroll
    for (int c=0;c<2;c++){
      int r = wid*16 + c*8 + srow;
      GL16(kbase + (size_t)(j0 + r)*2304 + (sbyte>>1), &Ks[bb][(wid*16 + c*8)*64]);
      GL16(vbase + (size_t)r*Tt + j0 + (sbyte>>1),     &Vs[bb][(wid*16 + c*8)*64]);
    }
  };
  float m_r[4], l_r[4];
  f32x4 o_acc[4] = {};
  #pragma unroll
  for (int jj=0;jj<4;jj++){ m_r[jj] = -1e30f; l_r[jj] = 0.f; }

  int njt = bx + 1;
  STAGEKV(0, 0);
  asm volatile("s_waitcnt vmcnt(0)" ::: "memory");
  __builtin_amdgcn_s_barrier();
  for (int t=0; t<njt; t++){
    int cur = t&1;
    if (t+1 < njt) STAGEKV(t+1, cur^1);
    int j0 = t*64;
    f32x4 sacc[4] = {};
    #pragma unroll
    for (int ks=0;ks<2;ks++){
      bf16x8 kf[4];
      #pragma unroll
      for (int ni=0;ni<4;ni++){
        int s16 = ni*16 + (lane&15);
        int kb = (ks*64 + (lane>>4)*16) ^ ((s16&7)<<4);
        kf[ni] = *(const bf16x8*)((const char*)&Ks[cur][0] + s16*128 + kb);
      }
      __builtin_amdgcn_s_setprio(1);
      #pragma unroll
      for (int ni=0;ni<4;ni++)
        sacc[ni] = __builtin_amdgcn_mfma_f32_16x16x32_bf16(qa[ks], kf[ni], sacc[ni], 0,0,0);
      __builtin_amdgcn_s_setprio(0);
    }
    float tmax[4];
    #pragma unroll
    for (int jj=0;jj<4;jj++) tmax[jj] = -1e30f;
    #pragma unroll
    for (int ni=0;ni<4;ni++)
      #pragma unroll
      for (int jj=0;jj<4;jj++){
        float v = sacc[ni][jj]*0.125f;
        int sg = j0 + ni*16 + (lane&15);
        int tg = q0 + wid*16 + (lane>>4)*4 + jj;
        v = (sg <= tg) ? v : -1e30f;
        sacc[ni][jj] = v;
        tmax[jj] = fmaxf(tmax[jj], v);
      }
    #pragma unroll
    for (int jj=0;jj<4;jj++){
      float tm = tmax[jj];
      tm = fmaxf(tm, __shfl_xor(tm,1)); tm = fmaxf(tm, __shfl_xor(tm,2));
      tm = fmaxf(tm, __shfl_xor(tm,4)); tm = fmaxf(tm, __shfl_xor(tm,8));
      float mn = fmaxf(m_r[jj], tm);
      float al = __expf(m_r[jj] - mn);
      m_r[jj] = mn;
      l_r[jj] *= al;
      tmax[jj] = al;
    }
    float tsum[4] = {};
    #pragma unroll
    for (int ni=0;ni<4;ni++)
      #pragma unroll
      for (int jj=0;jj<4;jj++){
        float p = __expf(sacc[ni][jj] - m_r[jj]);
        tsum[jj] += p;
        int pr = (lane>>4)*4 + jj;
        int pcb = (2*(ni*16 + (lane&15))) ^ ((pr&7)<<4);
        *(u16*)((char*)&Ps[wid][0] + pr*128 + pcb) = f2bf(p);
      }
    #pragma unroll
    for (int jj=0;jj<4;jj++){
      float ts = tsum[jj];
      ts += __shfl_xor(ts,1); ts += __shfl_xor(ts,2);
      ts += __shfl_xor(ts,4); ts += __shfl_xor(ts,8);
      l_r[jj] += ts;
      float al = tmax[jj];
      #pragma unroll
      for (int ni2=0;ni2<4;ni2++) o_acc[ni2][jj] *= al;
    }
    #pragma unroll
    for (int ks2=0;ks2<2;ks2++){
      bf16x8 pa, vf[4];
      int prr = lane&15;
      int pb = (ks2*64 + (lane>>4)*16) ^ ((prr&7)<<4);
      pa = *(const bf16x8*)((const char*)&Ps[wid][0] + prr*128 + pb);
      #pragma unroll
      for (int ni2=0;ni2<4;ni2++){
        int d16 = ni2*16 + (lane&15);
        int sb = (ks2*64 + (lane>>4)*16) ^ ((d16&7)<<4);
        vf[ni2] = *(const bf16x8*)((const char*)&Vs[cur][0] + d16*128 + sb);
      }
      __builtin_amdgcn_s_setprio(1);
      #pragma unroll
      for (int ni2=0;ni2<4;ni2++)
        o_acc[ni2] = __builtin_amdgcn_mfma_f32_16x16x32_bf16(pa, vf[ni2], o_acc[ni2], 0,0,0);
      __builtin_amdgcn_s_setprio(0);
    }
    asm volatile("s_waitcnt vmcnt(0) lgkmcnt(0)" ::: "memory");
    __builtin_amdgcn_s_barrier();
  }
  #pragma unroll
  for (int jj=0;jj<4;jj++){
    float inv = 1.0f / l_r[jj];
    int tok2 = q0 + wid*16 + (lane>>4)*4 + jj;
    size_t rb = (tokbase + tok2)*Cc + h*64;
    #pragma unroll
    for (int ni2=0;ni2<4;ni2++)
      y[rb + ni2*16 + (lane&15)] = f2bf(o_acc[ni2][jj] * inv);
  }
}

// -------- MFMA GEMM: BMxBN tile, BK in {32,64}, swizzled LDS rows, NBUF pipeline --------
template<int NBUF, int NTHR, int WN, int BM, int BN, int BK,
         bool BIAS, bool RESID, bool GELU, bool OUTBF, bool ROWSCAN, bool VFUSE>
__global__ __launch_bounds__(NTHR) void mm_kernel(
    const u16* __restrict__ A, const u16* __restrict__ Bm,
    const float* __restrict__ bias, const float* __restrict__ resid,
    void* __restrict__ out, u16* __restrict__ vt,
    int N, int K, int lda, int ldb, int ldc)
{
  constexpr int WAVES = NTHR/64;
  constexpr int WM    = WAVES/WN;
  constexpr int FM    = BM/(WM*16);
  constexpr int FN    = BN/(WN*16);
  constexpr int KSTEPS = BK/32;
  constexpr int CPW   = FN*16;
  constexpr int ESTR  = CPW + 4;
  constexpr int ABUF  = BM*BK;
  constexpr int BBUF  = BN*BK;
  constexpr int ARPW  = BM/WAVES;
  constexpr int BRPW  = BN/WAVES;
  constexpr int RPC   = (BK==64) ? 8 : 16;
  constexpr int ACALLS = ARPW/RPC;
  constexpr int BCALLS = BRPW/RPC;
  constexpr int LOADS = ACALLS + BCALLS;
  constexpr int SMEM_STAGE = NBUF*(ABUF+BBUF)*2;
  constexpr int SMEM_EPI   = WAVES*16*ESTR*4;
  constexpr int SMEMB = SMEM_STAGE > SMEM_EPI ? SMEM_STAGE : SMEM_EPI;
  __shared__ __align__(16) char smem[SMEMB];
  u16* As = (u16*)smem;
  u16* Bs = As + NBUF*ABUF;

  int bx = blockIdx.x, by = blockIdx.y;
  {                                    // bijective XCD swizzle (m204)
    int gx = gridDim.x;
    int nwg = gx * gridDim.y;
    int flat = by*gx + bx;
    int qq = nwg >> 3, rr = nwg & 7;
    int xcd = flat & 7, lid = flat >> 3;
    int swz = (xcd < rr) ? xcd*(qq+1) + lid : rr*(qq+1) + (xcd-rr)*qq + lid;
    bx = swz % gx; by = swz / gx;
  }
  int m0 = bx*BM, n0 = by*BN;
  int tid = threadIdx.x, lane = tid & 63, wid = tid >> 6;
  int r0 = (wid/WN)*(BM/WM), c0 = (wid%WN)*(BN/WN);
  int lrow = lane & 15;
  int rl, sswz;
  if constexpr (BK==64){ rl = lane>>3; sswz = ((lane&7) ^ (lane>>3)) * 8; }
  else                 { rl = lane>>2; sswz = ((lane&3) ^ ((lane>>3)&3)) * 8; }
  const u16* Ap = A + (size_t)(m0 + wid*ARPW + rl)*lda + sswz;
  const u16* Bp = Bm + (size_t)(n0 + wid*BRPW + rl)*ldb + sswz;
  int nt = K/BK;
  auto STAGE = [&](int t, int bb){
    int kk = t*BK;
    u16* Al = As + bb*ABUF + (wid*ARPW)*BK;
    #pragma unroll
    for (int c=0;c<ACALLS;c++)
      GL16(Ap + kk + (size_t)(c*RPC)*lda, Al + c*512);
    u16* Bl = Bs + bb*BBUF + (wid*BRPW)*BK;
    #pragma unroll
    for (int c=0;c<BCALLS;c++)
      GL16(Bp + kk + (size_t)(c*RPC)*ldb, Bl + c*512);
  };
  f32x4 acc[FM][FN] = {};
  if constexpr (NBUF==2){
    STAGE(0, 0);
    WAITVM(0);
    __builtin_amdgcn_s_barrier();
  } else {
    STAGE(0, 0);
    if (nt > 1) STAGE(1, 1);
    WAITVM(LOADS);
    __builtin_amdgcn_s_barrier();
  }
  for (int t = 0; t < nt; t++){
    int bb = (NBUF==2) ? (t & 1) : (t % 3);
    if constexpr (NBUF==2){
      if (t+1 < nt) STAGE(t+1, (t+1)&1);
    } else {
      if (t+2 < nt) STAGE(t+2, (t+2)%3);
    }
    const char* Ab2 = (const char*)(As + bb*ABUF);
    const char* Bb2 = (const char*)(Bs + bb*BBUF);
    #pragma unroll
    for (int ks=0;ks<KSTEPS;ks++){
      int cof;
      if constexpr (BK==64) cof = ((ks*4 + (lane>>4)) ^ (lane&7)) << 4;
      else                  cof = ((lane>>4) ^ (((lane&15)>>1)&3)) << 4;
      bf16x8 af[FM], bfr[FN];
      #pragma unroll
      for (int m=0;m<FM;m++) af[m] = *(const bf16x8*)(Ab2 + (r0 + m*16 + lrow)*(BK*2) + cof);
      #pragma unroll
      for (int n=0;n<FN;n++) bfr[n] = *(const bf16x8*)(Bb2 + (c0 + n*16 + lrow)*(BK*2) + cof);
      #pragma unroll
      for (int m=0;m<FM;m++)
        #pragma unroll
        for (int n=0;n<FN;n++)
          acc[m][n] = __builtin_amdgcn_mfma_f32_16x16x32_bf16(af[m], bfr[n], acc[m][n], 0,0,0);
    }
    if constexpr (NBUF==2){
      asm volatile("s_waitcnt vmcnt(0) lgkmcnt(0)" ::: "memory");
    } else {
      if (t+2 < nt) WAITVM(LOADS); else WAITVM(0);
    }
    __builtin_amdgcn_s_barrier();
  }

  // ---- epilogue: per-wave-private LDS transpose tile, coalesced stores ----
  float* ebuf = (float*)smem + wid*16*ESTR;
  int er = lane >> 2;
  int ec = (lane & 3) * (CPW/4);
  #pragma unroll
  for (int m=0;m<FM;m++){
    #pragma unroll
    for (int n=0;n<FN;n++)
      #pragma unroll
      for (int j=0;j<4;j++)
        ebuf[((lane>>4)*4+j)*ESTR + n*16 + (lane&15)] = acc[m][n][j];
    __builtin_amdgcn_s_waitcnt(0);     // lgkm drain for own-wave LDS RAW
    if constexpr (ROWSCAN){
      #pragma unroll
      for (int rr2=0; rr2<16; rr2++){
        int gr2 = m0 + r0 + m*16 + rr2;
        int gc2 = n0 + c0 + lane;
        float v = ebuf[rr2*ESTR + lane];
        if (gc2 < N)
          __builtin_nontemporal_store(v, &((float*)out)[(size_t)gr2*ldc + gc2]);
      }
    } else {
      int grow = m0 + r0 + m*16 + er;
      int gcol = n0 + c0 + ec;
      size_t rbase = (size_t)grow*ldc;
      if constexpr (OUTBF){
        u16 tmp[CPW/4];
        #pragma unroll
        for (int q=0;q<FN;q++){
          float4 v = *(const float4*)&ebuf[er*ESTR + ec + q*4];
          float f0=v.x, f1=v.y, f2=v.z, f3=v.w;
          if (BIAS){
            float4 b4 = *(const float4*)&bias[gcol + q*4];
            f0+=b4.x; f1+=b4.y; f2+=b4.z; f3+=b4.w;
          }
          if (GELU){
            f0 = 0.5f*f0*(1.f+erff(f0*0.70710678118654752f));
            f1 = 0.5f*f1*(1.f+erff(f1*0.70710678118654752f));
            f2 = 0.5f*f2*(1.f+erff(f2*0.70710678118654752f));
            f3 = 0.5f*f3*(1.f+erff(f3*0.70710678118654752f));
          }
          tmp[q*4+0]=f2bf(f0); tmp[q*4+1]=f2bf(f1);
          tmp[q*4+2]=f2bf(f2); tmp[q*4+3]=f2bf(f3);
        }
        // v-region (cols>=1536) is only consumed via vT -> skip qkv store there
        if (!VFUSE || gcol < 1536){
          #pragma unroll
          for (int s2=0; s2<CPW/32; s2++)
            *(u16x8*)&((u16*)out)[rbase + gcol + s2*8] = *(const u16x8*)&tmp[s2*8];
        }
        if constexpr (VFUSE){
          if (gcol >= 1536){
            int hh = (gcol - 1536) >> 6;
            int d0 = (gcol - 1536) & 63;
            int b  = grow >> 10;          // Tt = 1024
            int tt = grow & (Tt-1);
            u16* vp = vt + ((size_t)(b*Hh + hh)*64 + d0)*Tt + tt;
            #pragma unroll
            for (int i=0;i<CPW/4;i++)
              vp[(size_t)i*Tt] = tmp[i];
          }
        }
      } else {
        #pragma unroll
        for (int q=0;q<FN;q++){
          float4 v = *(const float4*)&ebuf[er*ESTR + ec + q*4];
          float f0=v.x, f1=v.y, f2=v.z, f3=v.w;
          if (BIAS){
            float4 b4 = *(const float4*)&bias[gcol + q*4];
            f0+=b4.x; f1+=b4.y; f2+=b4.z; f3+=b4.w;
          }
          if (GELU){
            f0 = 0.5f*f0*(1.f+erff(f0*0.70710678118654752f));
            f1 = 0.5f*f1*(1.f+erff(f1*0.70710678118654752f));
            f2 = 0.5f*f2*(1.f+erff(f2*0.70710678118654752f));
            f3 = 0.5f*f3*(1.f+erff(f3*0.70710678118654752f));
          }
          if (RESID){
            float4 r4 = *(const float4*)&resid[rbase + gcol + q*4];
            f0+=r4.x; f1+=r4.y; f2+=r4.z; f3+=r4.w;
          }
          float4 o4; o4.x=f0; o4.y=f1; o4.z=f2; o4.w=f3;
          *(float4*)&((float*)out)[rbase + gcol + q*4] = o4;
        }
      }
    }
  }
}

// ---------------- orchestration ----------------
extern "C" void kernel_launch(void* const* d_in, const int* in_sizes, int n_in,
                              void* d_out, int out_size, void* d_ws, size_t ws_size,
                              hipStream_t stream){
  const int*   idx  = (const int*)d_in[0];
  const float* tok  = (const float*)d_in[1];
  const float* pos  = (const float*)d_in[2];
  const float* ln1g = (const float*)d_in[3];
  const float* ln1b = (const float*)d_in[4];
  const float* Wq   = (const float*)d_in[5];
  const float* bq   = (const float*)d_in[6];
  const float* Wk   = (const float*)d_in[7];
  const float* bk   = (const float*)d_in[8];
  const float* Wv   = (const float*)d_in[9];
  const float* bv   = (const float*)d_in[10];
  const float* Wp   = (const float*)d_in[11];
  const float* bp   = (const float*)d_in[12];
  const float* ln2g = (const float*)d_in[13];
  const float* ln2b = (const float*)d_in[14];
  const float* Wf1  = (const float*)d_in[15];
  const float* bf1  = (const float*)d_in[16];
  const float* Wf2  = (const float*)d_in[17];
  const float* bf2  = (const float*)d_in[18];
  const float* lnfg = (const float*)d_in[19];
  const float* lnfb = (const float*)d_in[20];
  const float* headW= (const float*)d_in[21];
  float* outp = (float*)d_out;

  char* w = (char*)d_ws;
  u16* wqkvT = (u16*)w;  w += (size_t)Ll*2304*768*2;
  u16* wpT   = (u16*)w;  w += (size_t)Ll*768*768*2;
  u16* wf1T  = (u16*)w;  w += (size_t)Ll*3072*768*2;
  u16* wf2T  = (u16*)w;  w += (size_t)Ll*768*3072*2;
  u16* headT = (u16*)w;  w += (size_t)VPAD*768*2;
  float* bqkv= (float*)w;w += (size_t)Ll*2304*4;
  float* x   = (float*)w;w += (size_t)NTOK*Cc*4;
  u16* h     = (u16*)w;  w += (size_t)NTOK*Cc*2;
  u16* qkv   = (u16*)w;  w += (size_t)NTOK*2304*2;
  u16* vT    = (u16*)w;  w += (size_t)Bsz*Hh*64*Tt*2;
  u16* y     = (u16*)w;  w += (size_t)NTOK*Cc*2;
  u16* ff    = (u16*)w;  w += (size_t)NTOK*4*Cc*2;

  wtrans4_kernel<<<dim3(12,12,4*Ll), 256, 0, stream>>>(Wq, Wk, Wv, Wp, wqkvT, wpT);
  wtrans_kernel<<<dim3(48,12,Ll), 256, 0, stream>>>(Wf1, wf1T,          768, 3072, 3072, (size_t)Cc*4*Cc, (size_t)3072*768);
  wtrans_kernel<<<dim3(12,48,Ll), 256, 0, stream>>>(Wf2, wf2T,          3072, 768, 768, (size_t)4*Cc*Cc, (size_t)768*3072);
  wtrans_kernel<<<dim3(VPAD/64,12,1), 256, 0, stream>>>(headW, headT, 768, Vv, VPAD, 0, 0);
  bconcat_kernel<<<(Ll*2304+255)/256, 256, 0, stream>>>(bq, bk, bv, bqkv);

  embed_kernel<<<NTOK*(Cc/4)/256, 256, 0, stream>>>(idx, tok, pos, x);

  for (int l=0;l<Ll;l++){
    ln_kernel<<<NTOK, 256, 0, stream>>>(x, ln1g+l*Cc, ln1b+l*Cc, h);
    // qkv GEMM with fused v-transpose into vT (v-region global store skipped)
    mm_kernel<2,256,2,64,128,64,true,false,false,true,false,true><<<dim3(32,18,1), 256, 0, stream>>>(
        h, wqkvT+(size_t)l*2304*768, bqkv+l*2304, nullptr, qkv, vT, 2304, 768, 768, 768, 2304);
    flash_kernel<<<dim3(Tt/64, Bsz*Hh), 256, 0, stream>>>(qkv, vT, y);
    mm_kernel<3,256,2,64,64,64,true,true,false,false,false,false><<<dim3(32,12,1), 256, 0, stream>>>(
        y, wpT+(size_t)l*768*768, bp+l*Cc, x, x, nullptr, 768, 768, 768, 768, 768);
    ln_kernel<<<NTOK, 256, 0, stream>>>(x, ln2g+l*Cc, ln2b+l*Cc, h);
    mm_kernel<2,256,2,64,128,64,true,false,true,true,false,false><<<dim3(32,24,1), 256, 0, stream>>>(
        h, wf1T+(size_t)l*3072*768, bf1+(size_t)l*4*Cc, nullptr, ff, nullptr, 3072, 768, 768, 768, 3072);
    mm_kernel<3,256,2,64,64,64,true,true,false,false,false,false><<<dim3(32,12,1), 256, 0, stream>>>(
        ff, wf2T+(size_t)l*768*3072, bf2+l*Cc, x, x, nullptr, 768, 3072, 3072, 3072, 768);
  }
  ln_kernel<<<NTOK, 256, 0, stream>>>(x, lnfg, lnfb, h);
  // head: R9 optimum — 128x128 tile, BK=32 swz, NBUF=2, 32KB LDS, 4 waves, 5 blk/CU
  mm_kernel<2,256,2,128,128,32,false,false,false,false,true,false><<<dim3(16,VPAD/128,1), 256, 0, stream>>>(
      h, headT, nullptr, nullptr, outp, nullptr, Vv, 768, 768, 768, Vv);
}